// Round 5
// baseline (8332.458 us; speedup 1.0000x reference)
//
#include <hip/hip_runtime.h>

typedef __attribute__((ext_vector_type(8))) short bf16x8;
typedef __attribute__((ext_vector_type(4))) float f32x4;

#define DEV static __device__ __forceinline__

DEV unsigned short f2bf(float f) {
    union { float f; unsigned u; } a; a.f = f;
    unsigned r = a.u + 0x7FFFu + ((a.u >> 16) & 1u);
    return (unsigned short)(r >> 16);
}
DEV float bfl(unsigned u) { union { unsigned u; float f; } a; a.u = u << 16; return a.f; }
DEV float bfh(unsigned u) { union { unsigned u; float f; } a; a.u = u & 0xFFFF0000u; return a.f; }

// ---------------------------------------------------------------- weight prep
// Btw plane p: Bt[p][c][k] = W[k][c] bf16. p=0 w_in2, p=1 w_seg2,
// p in [2,62): iter i=(p-2)/15, t=(p-2)%15 (0=ctr,1..6=pre,7..12=suc,13=left,14=right),
// p in [62,66): ctr2_w[i].
__global__ void wprep(const float* __restrict__ w_in2, const float* __restrict__ w_seg2,
                      const float* __restrict__ ctr_w, const float* __restrict__ pre_w,
                      const float* __restrict__ suc_w, const float* __restrict__ left_w,
                      const float* __restrict__ right_w, const float* __restrict__ ctr2_w,
                      unsigned short* __restrict__ Btw) {
    int idx = blockIdx.x * 256 + threadIdx.x;
    if (idx >= 66 * 16384) return;
    int p = idx >> 14, within = idx & 16383;
    int c = within >> 7, k = within & 127;
    const float* src;
    if (p == 0) src = w_in2;
    else if (p == 1) src = w_seg2;
    else if (p < 62) {
        int pi = p - 2; int i = pi / 15, t = pi % 15;
        if (t == 0) src = ctr_w + i * 16384;
        else if (t < 7) src = pre_w + (i * 6 + (t - 1)) * 16384;
        else if (t < 13) src = suc_w + (i * 6 + (t - 7)) * 16384;
        else if (t == 13) src = left_w + i * 16384;
        else src = right_w + i * 16384;
    } else src = ctr2_w + (p - 62) * 16384;
    Btw[idx] = f2bf(src[k * 128 + c]);
}

// ---------------------------------------------------------------- per-type CSR build
// type tags t=1..14 (1..6 pre, 7..12 suc, 13 left, 14 right); tt = t-1.
// edata segment base: tt<=11 -> tt*E; tt==12 -> 12E; tt==13 -> 12E+E2.
DEV int edge_decode(int e, int E, int E2,
                    const int* pre_u, const int* pre_v, const int* suc_u, const int* suc_v,
                    const int* left_u, const int* left_v, const int* right_u, const int* right_v,
                    int* u, int* v) {
    if (e < 12 * E) {
        int s = e / E, off = e - s * E;
        if (s < 6) { *u = pre_u[s * E + off]; *v = pre_v[s * E + off]; }
        else { *u = suc_u[(s - 6) * E + off]; *v = suc_v[(s - 6) * E + off]; }
        return 1 + s;
    }
    int e2 = e - 12 * E;
    if (e2 < E2) { *u = left_u[e2]; *v = left_v[e2]; return 13; }
    *u = right_u[e2 - E2]; *v = right_v[e2 - E2]; return 14;
}

__global__ void edge_count14(const int* __restrict__ pre_u, const int* __restrict__ pre_v,
                             const int* __restrict__ suc_u, const int* __restrict__ suc_v,
                             const int* __restrict__ left_u, const int* __restrict__ left_v,
                             const int* __restrict__ right_u, const int* __restrict__ right_v,
                             int E, int E2, int Mtot, int N, int* __restrict__ cnt14) {
    int e = blockIdx.x * 256 + threadIdx.x;
    if (e >= Mtot) return;
    int u, v;
    int t = edge_decode(e, E, E2, pre_u, pre_v, suc_u, suc_v, left_u, left_v, right_u, right_v, &u, &v);
    atomicAdd(&cnt14[(size_t)(t - 1) * N + u], 1);
}

__global__ void edge_fill14(const int* __restrict__ pre_u, const int* __restrict__ pre_v,
                            const int* __restrict__ suc_u, const int* __restrict__ suc_v,
                            const int* __restrict__ left_u, const int* __restrict__ left_v,
                            const int* __restrict__ right_u, const int* __restrict__ right_v,
                            int E, int E2, int Mtot, int N,
                            const int* __restrict__ rowptrs, int* __restrict__ cur,
                            int* __restrict__ edata) {
    int e = blockIdx.x * 256 + threadIdx.x;
    if (e >= Mtot) return;
    int u, v;
    int t = edge_decode(e, E, E2, pre_u, pre_v, suc_u, suc_v, left_u, left_v, right_u, right_v, &u, &v);
    int tt = t - 1;
    int pos = atomicAdd(&cur[(size_t)tt * N + u], 1);
    size_t base = (tt <= 11) ? (size_t)tt * E : (size_t)12 * E + (size_t)(tt - 12) * E2;
    edata[base + rowptrs[(size_t)tt * (N + 1) + u] + pos] = ((u & 63) << 18) | v;
}

// typed exclusive scans: blockIdx.y (or .x for scanB2) = type
__global__ void scanA2(const int* __restrict__ cnt14, int N, int* __restrict__ rowptrs,
                       int* __restrict__ bsum) {
    const int* cnt = cnt14 + (size_t)blockIdx.y * N;
    int* rowptr = rowptrs + (size_t)blockIdx.y * (N + 1);
    int* bs = bsum + blockIdx.y * 128;
    __shared__ int lds[256];
    int tid = threadIdx.x;
    int base = blockIdx.x * 2048 + tid * 8;
    int v[8]; int s = 0;
#pragma unroll
    for (int j = 0; j < 8; ++j) { int i = base + j; v[j] = (i < N) ? cnt[i] : 0; s += v[j]; }
    lds[tid] = s; __syncthreads();
    for (int d = 1; d < 256; d <<= 1) {
        int t2 = (tid >= d) ? lds[tid - d] : 0;
        __syncthreads();
        lds[tid] += t2;
        __syncthreads();
    }
    int excl = lds[tid] - s;
    if (tid == 255) bs[blockIdx.x] = lds[255];
    int run = excl;
#pragma unroll
    for (int j = 0; j < 8; ++j) { int i = base + j; if (i < N) rowptr[i] = run; run += v[j]; }
}

__global__ void scanB2(int* __restrict__ bsum, int nb, int* __restrict__ rowptrs, int N) {
    int* bs = bsum + blockIdx.x * 128;
    __shared__ int lds[128];
    int tid = threadIdx.x;
    int v = (tid < nb) ? bs[tid] : 0;
    lds[tid] = v; __syncthreads();
    for (int d = 1; d < 128; d <<= 1) {
        int t2 = (tid >= d) ? lds[tid - d] : 0;
        __syncthreads();
        lds[tid] += t2;
        __syncthreads();
    }
    if (tid < nb) bs[tid] = lds[tid] - v;
    if (tid == 127) rowptrs[(size_t)blockIdx.x * (N + 1) + N] = lds[127];
}

__global__ void scanC2(int* __restrict__ rowptrs, const int* __restrict__ bsum, int N) {
    int i = blockIdx.x * 256 + threadIdx.x;
    if (i < N) rowptrs[(size_t)blockIdx.y * (N + 1) + i] += bsum[blockIdx.y * 128 + (i >> 11)];
}

// ---------------------------------------------------------------- encoders (first linear+relu)
__global__ void enc(const float* __restrict__ ctrs, const float* __restrict__ feats,
                    const float* __restrict__ w_in1, const float* __restrict__ b_in1,
                    const float* __restrict__ w_seg1, const float* __restrict__ b_seg1,
                    unsigned short* __restrict__ h_in, unsigned short* __restrict__ h_seg, int N) {
    int idx = blockIdx.x * 256 + threadIdx.x;
    if (idx >= N * 128) return;
    int n = idx >> 7, c = idx & 127;
    float x0 = ctrs[2 * n], x1 = ctrs[2 * n + 1];
    float h = fmaxf(x0 * w_in1[c] + x1 * w_in1[128 + c] + b_in1[c], 0.f);
    h_in[idx] = f2bf(h);
    x0 = feats[2 * n]; x1 = feats[2 * n + 1];
    h = fmaxf(x0 * w_seg1[c] + x1 * w_seg1[128 + c] + b_seg1[c], 0.f);
    h_seg[idx] = f2bf(h);
}

// ---------------------------------------------------------------- encoder GEMM (single plane)
enum { MODE_GN = 1, MODE_GNADD = 2 };

template <int MODE>
__global__ __launch_bounds__(256, 2) void gemm128(
    const unsigned short* __restrict__ A,   // [M][128] bf16
    const unsigned short* __restrict__ Bt,  // [128][128] bf16, Bt[c][k]
    int M,
    const unsigned short* __restrict__ resb,  // MODE_GNADD residual bf16
    float* __restrict__ outf,                 // optional f32 out
    unsigned short* __restrict__ outb,        // bf16 out
    const float* __restrict__ gw, const float* __restrict__ gb) {
    __shared__ char Asm[32768];
    __shared__ char Bsm[32768];
    const int tid = threadIdx.x;
    const int wv = tid >> 6, ln = tid & 63;
    const int q = ln >> 4, r = ln & 15;
    const int m0 = blockIdx.x * 128;

#pragma unroll
    for (int s = 0; s < 8; ++s) {
        int f = s * 256 + tid;
        int row = f >> 4, ck = f & 15;
        int grow = m0 + row; if (grow >= M) grow = M - 1;
        int4 v = *(const int4*)(A + (size_t)grow * 128 + ck * 8);
        *(int4*)(Asm + row * 256 + ((ck * 16) ^ ((row & 7) << 4))) = v;
    }
#pragma unroll
    for (int s = 0; s < 8; ++s) {
        int f = s * 256 + tid;
        int c = f >> 4, ck = f & 15;
        int4 v = *(const int4*)(Bt + c * 128 + ck * 8);
        *(int4*)(Bsm + c * 256 + ((ck * 16) ^ ((c & 7) << 4))) = v;
    }
    __syncthreads();

    f32x4 acc[2][8];
#pragma unroll
    for (int fj = 0; fj < 2; ++fj)
#pragma unroll
        for (int ci = 0; ci < 8; ++ci) acc[fj][ci] = (f32x4)(0.f);

#pragma unroll
    for (int k0 = 0; k0 < 128; k0 += 32) {
        int kb = k0 * 2 + q * 16;
        bf16x8 wf[8], ff[2];
#pragma unroll
        for (int ci = 0; ci < 8; ++ci) {
            int c = ci * 16 + r;
            wf[ci] = *(const bf16x8*)(Bsm + c * 256 + (kb ^ ((c & 7) << 4)));
        }
#pragma unroll
        for (int fj = 0; fj < 2; ++fj) {
            int row = wv * 32 + fj * 16 + r;
            ff[fj] = *(const bf16x8*)(Asm + row * 256 + (kb ^ ((row & 7) << 4)));
        }
#pragma unroll
        for (int fj = 0; fj < 2; ++fj)
#pragma unroll
            for (int ci = 0; ci < 8; ++ci)
                acc[fj][ci] = __builtin_amdgcn_mfma_f32_16x16x32_bf16(wf[ci], ff[fj], acc[fj][ci], 0, 0, 0);
    }

#pragma unroll
    for (int fj = 0; fj < 2; ++fj) {
        float s = 0.f;
#pragma unroll
        for (int ci = 0; ci < 8; ++ci) {
            f32x4 a = acc[fj][ci];
            s += a[0] + a[1] + a[2] + a[3];
        }
        s += __shfl_xor(s, 16); s += __shfl_xor(s, 32);
        float mean = s * (1.f / 128.f);
        float vs = 0.f;
#pragma unroll
        for (int ci = 0; ci < 8; ++ci) {
            f32x4 a = acc[fj][ci];
#pragma unroll
            for (int j = 0; j < 4; ++j) { float d = a[j] - mean; vs += d * d; }
        }
        vs += __shfl_xor(vs, 16); vs += __shfl_xor(vs, 32);
        float inv = rsqrtf(vs * (1.f / 128.f) + 1e-5f);
        int row = m0 + wv * 32 + fj * 16 + r;
        if (row < M) {
#pragma unroll
            for (int ci = 0; ci < 8; ++ci) {
                int col = ci * 16 + q * 4;
                f32x4 a = acc[fj][ci];
                float4 gv = *(const float4*)(gw + col);
                float4 bv = *(const float4*)(gb + col);
                float y0 = (a[0] - mean) * inv * gv.x + bv.x;
                float y1 = (a[1] - mean) * inv * gv.y + bv.y;
                float y2 = (a[2] - mean) * inv * gv.z + bv.z;
                float y3 = (a[3] - mean) * inv * gv.w + bv.w;
                if (MODE == MODE_GNADD) {
                    int2 rv = *(const int2*)(resb + (size_t)row * 128 + col);
                    y0 = fmaxf(y0 + bfl((unsigned)rv.x), 0.f);
                    y1 = fmaxf(y1 + bfh((unsigned)rv.x), 0.f);
                    y2 = fmaxf(y2 + bfl((unsigned)rv.y), 0.f);
                    y3 = fmaxf(y3 + bfh((unsigned)rv.y), 0.f);
                    if (outf) {
                        float4 o; o.x = y0; o.y = y1; o.z = y2; o.w = y3;
                        *(float4*)(outf + (size_t)row * 128 + col) = o;
                    }
                }
                unsigned lo = (unsigned)f2bf(y0) | ((unsigned)f2bf(y1) << 16);
                unsigned hi = (unsigned)f2bf(y2) | ((unsigned)f2bf(y3) << 16);
                int2 pk; pk.x = (int)lo; pk.y = (int)hi;
                *(int2*)(outb + (size_t)row * 128 + col) = pk;
            }
        }
    }
}

// ---------------------------------------------------------------- fused iteration kernel
// Per 64-node tile: for t=0..14 aggregate feat rows (LDS f32 atomics; t=0 = own
// feat rows) then MFMA agg@W_t into persistent acc. GN+ReLU -> P(LDS bf16) ->
// MFMA P@ctr2 -> GN + residual + ReLU -> featB (+featf on last iter).
template <int LASTI>
__global__ __launch_bounds__(256, 2) void fuse_gemm(
    const unsigned* __restrict__ featA,       // [N][64] packed 2xbf16 words
    unsigned short* __restrict__ featB,       // [N][128] bf16 out
    float* __restrict__ featf,                // [N][128] f32 out (LASTI)
    const unsigned short* __restrict__ Bt15,  // 15 planes: ctr, pre x6, suc x6, left, right
    const unsigned short* __restrict__ Bc2,   // ctr2 plane
    const int* __restrict__ rowptrs,          // 14*(N+1)
    const int* __restrict__ edata,
    int N, int E, int E2,
    const float* __restrict__ gw1, const float* __restrict__ gb1,
    const float* __restrict__ gw2, const float* __restrict__ gb2) {
    __shared__ float aggF[64 * 128];   // 32KB, XOR-swizzled rows
    __shared__ char Bsm[32768];
    const int tid = threadIdx.x;
    const int wv = tid >> 6, ln = tid & 63;
    const int q = ln >> 4, r = ln & 15;
    const int m0 = blockIdx.x * 64;
    const int row = wv * 16 + r;       // this lane's output row (local)
    const int swR = (row & 7) << 2;    // f32-unit XOR for this row
    const int swB = (row & 7) << 4;    // byte XOR for bf16 P reads

    f32x4 acc[8];
#pragma unroll
    for (int ci = 0; ci < 8; ++ci) acc[ci] = (f32x4)(0.f);

    for (int t = 0; t < 15; ++t) {
        __syncthreads();  // previous MFMA done with Bsm/aggF
        // stage W_t
        {
            const unsigned short* Bp = Bt15 + (size_t)t * 16384;
#pragma unroll
            for (int s = 0; s < 8; ++s) {
                int f = s * 256 + tid;
                int c = f >> 4, ck = f & 15;
                int4 v = *(const int4*)(Bp + c * 128 + ck * 8);
                *(int4*)(Bsm + c * 256 + ((ck * 16) ^ ((c & 7) << 4))) = v;
            }
        }
        // init aggF
        if (t == 0) {
            int irow = tid >> 2, seg = tid & 3;
            int gr = m0 + irow; if (gr >= N) gr = N - 1;
            const unsigned* src = featA + (size_t)gr * 64 + seg * 16;
            float* dst = aggF + irow * 128;
            int sw = (irow & 7) << 2;
#pragma unroll
            for (int i2 = 0; i2 < 4; ++i2) {
                uint4 w4 = *(const uint4*)(src + i2 * 4);
                f32x4 e0, e1;
                e0[0] = bfl(w4.x); e0[1] = bfh(w4.x); e0[2] = bfl(w4.y); e0[3] = bfh(w4.y);
                e1[0] = bfl(w4.z); e1[1] = bfh(w4.z); e1[2] = bfl(w4.w); e1[3] = bfh(w4.w);
                int c0 = seg * 32 + i2 * 8;
                *(f32x4*)(dst + (c0 ^ sw)) = e0;
                *(f32x4*)(dst + ((c0 + 4) ^ sw)) = e1;
            }
        } else {
#pragma unroll
            for (int s = 0; s < 8; ++s)
                *(f32x4*)(aggF + (s * 256 + tid) * 4) = (f32x4)(0.f);
        }
        __syncthreads();
        if (t > 0) {
            int tt = t - 1;
            size_t base = (tt <= 11) ? (size_t)tt * E : (size_t)12 * E + (size_t)(tt - 12) * E2;
            const int* rp = rowptrs + (size_t)tt * (N + 1);
            int hi2 = m0 + 64; if (hi2 > N) hi2 = N;
            int r0 = rp[m0], r1 = rp[hi2];
            const int* ed = edata + base;
            int nE = r1 - r0;
            int col = 2 * ln;
            for (int cb = 16 * wv; cb < nE; cb += 64) {
                int cnt2 = nE - cb; if (cnt2 > 16) cnt2 = 16;
                int my = (ln < cnt2) ? ed[r0 + cb + ln] : 0;
                for (int j = 0; j < cnt2; j += 4) {
                    int w0 = __shfl(my, j);
                    int w1 = __shfl(my, j + 1);
                    int w2 = __shfl(my, j + 2);
                    int w3 = __shfl(my, j + 3);
                    unsigned p0 = featA[(size_t)(unsigned)(w0 & 0x3FFFF) * 64 + ln];
                    unsigned p1 = featA[(size_t)(unsigned)(w1 & 0x3FFFF) * 64 + ln];
                    unsigned p2 = featA[(size_t)(unsigned)(w2 & 0x3FFFF) * 64 + ln];
                    unsigned p3 = featA[(size_t)(unsigned)(w3 & 0x3FFFF) * 64 + ln];
                    int u0 = w0 >> 18, u1 = w1 >> 18, u2 = w2 >> 18, u3 = w3 >> 18;
                    int i0 = u0 * 128 + (col ^ ((u0 & 7) << 2));
                    atomicAdd(&aggF[i0], bfl(p0));
                    atomicAdd(&aggF[i0 + 1], bfh(p0));
                    if (j + 1 < cnt2) {
                        int i1 = u1 * 128 + (col ^ ((u1 & 7) << 2));
                        atomicAdd(&aggF[i1], bfl(p1));
                        atomicAdd(&aggF[i1 + 1], bfh(p1));
                    }
                    if (j + 2 < cnt2) {
                        int i2x = u2 * 128 + (col ^ ((u2 & 7) << 2));
                        atomicAdd(&aggF[i2x], bfl(p2));
                        atomicAdd(&aggF[i2x + 1], bfh(p2));
                    }
                    if (j + 3 < cnt2) {
                        int i3 = u3 * 128 + (col ^ ((u3 & 7) << 2));
                        atomicAdd(&aggF[i3], bfl(p3));
                        atomicAdd(&aggF[i3 + 1], bfh(p3));
                    }
                }
            }
            __syncthreads();
        }
        // MFMA accumulate: acc += agg @ W_t
#pragma unroll
        for (int k0 = 0; k0 < 128; k0 += 32) {
            int c0 = k0 + q * 8;
            f32x4 fa = *(const f32x4*)(aggF + row * 128 + (c0 ^ swR));
            f32x4 fb = *(const f32x4*)(aggF + row * 128 + ((c0 + 4) ^ swR));
            bf16x8 ff;
            ff[0] = (short)f2bf(fa[0]); ff[1] = (short)f2bf(fa[1]);
            ff[2] = (short)f2bf(fa[2]); ff[3] = (short)f2bf(fa[3]);
            ff[4] = (short)f2bf(fb[0]); ff[5] = (short)f2bf(fb[1]);
            ff[6] = (short)f2bf(fb[2]); ff[7] = (short)f2bf(fb[3]);
            int kb = k0 * 2 + q * 16;
#pragma unroll
            for (int ci = 0; ci < 8; ++ci) {
                int c = ci * 16 + r;
                bf16x8 wf = *(const bf16x8*)(Bsm + c * 256 + (kb ^ ((c & 7) << 4)));
                acc[ci] = __builtin_amdgcn_mfma_f32_16x16x32_bf16(wf, ff, acc[ci], 0, 0, 0);
            }
        }
    }

    // ---- epilogue 1: GN(norm) + ReLU -> py (bf16 packed)
    int2 py[8];
    {
        float s = 0.f;
#pragma unroll
        for (int ci = 0; ci < 8; ++ci) {
            f32x4 a = acc[ci];
            s += a[0] + a[1] + a[2] + a[3];
        }
        s += __shfl_xor(s, 16); s += __shfl_xor(s, 32);
        float mean = s * (1.f / 128.f);
        float vs = 0.f;
#pragma unroll
        for (int ci = 0; ci < 8; ++ci) {
            f32x4 a = acc[ci];
#pragma unroll
            for (int j = 0; j < 4; ++j) { float d = a[j] - mean; vs += d * d; }
        }
        vs += __shfl_xor(vs, 16); vs += __shfl_xor(vs, 32);
        float inv = rsqrtf(vs * (1.f / 128.f) + 1e-5f);
#pragma unroll
        for (int ci = 0; ci < 8; ++ci) {
            int cl = ci * 16 + q * 4;
            f32x4 a = acc[ci];
            float4 gv = *(const float4*)(gw1 + cl);
            float4 bv = *(const float4*)(gb1 + cl);
            float y0 = fmaxf((a[0] - mean) * inv * gv.x + bv.x, 0.f);
            float y1 = fmaxf((a[1] - mean) * inv * gv.y + bv.y, 0.f);
            float y2 = fmaxf((a[2] - mean) * inv * gv.z + bv.z, 0.f);
            float y3 = fmaxf((a[3] - mean) * inv * gv.w + bv.w, 0.f);
            py[ci].x = (int)((unsigned)f2bf(y0) | ((unsigned)f2bf(y1) << 16));
            py[ci].y = (int)((unsigned)f2bf(y2) | ((unsigned)f2bf(y3) << 16));
        }
    }
    __syncthreads();  // all waves done reading aggF/Bsm
    // store P (feat1 tile, bf16, Asm-style layout) + stage ctr2 weights
    char* P = (char*)aggF;
#pragma unroll
    for (int ci = 0; ci < 8; ++ci)
        *(int2*)(P + row * 256 + ((ci * 32 + q * 8) ^ swB)) = py[ci];
#pragma unroll
    for (int s = 0; s < 8; ++s) {
        int f = s * 256 + tid;
        int c = f >> 4, ck = f & 15;
        int4 v = *(const int4*)(Bc2 + c * 128 + ck * 8);
        *(int4*)(Bsm + c * 256 + ((ck * 16) ^ ((c & 7) << 4))) = v;
    }
    __syncthreads();

    // ---- second GEMM: acc2 = P @ ctr2
    f32x4 acc2[8];
#pragma unroll
    for (int ci = 0; ci < 8; ++ci) acc2[ci] = (f32x4)(0.f);
#pragma unroll
    for (int k0 = 0; k0 < 128; k0 += 32) {
        int kb = k0 * 2 + q * 16;
        bf16x8 ff = *(const bf16x8*)(P + row * 256 + (kb ^ swB));
#pragma unroll
        for (int ci = 0; ci < 8; ++ci) {
            int c = ci * 16 + r;
            bf16x8 wf = *(const bf16x8*)(Bsm + c * 256 + (kb ^ ((c & 7) << 4)));
            acc2[ci] = __builtin_amdgcn_mfma_f32_16x16x32_bf16(wf, ff, acc2[ci], 0, 0, 0);
        }
    }

    // ---- epilogue 2: GN(ctr2) + residual + ReLU -> featB (+featf)
    {
        float s = 0.f;
#pragma unroll
        for (int ci = 0; ci < 8; ++ci) {
            f32x4 a = acc2[ci];
            s += a[0] + a[1] + a[2] + a[3];
        }
        s += __shfl_xor(s, 16); s += __shfl_xor(s, 32);
        float mean = s * (1.f / 128.f);
        float vs = 0.f;
#pragma unroll
        for (int ci = 0; ci < 8; ++ci) {
            f32x4 a = acc2[ci];
#pragma unroll
            for (int j = 0; j < 4; ++j) { float d = a[j] - mean; vs += d * d; }
        }
        vs += __shfl_xor(vs, 16); vs += __shfl_xor(vs, 32);
        float inv = rsqrtf(vs * (1.f / 128.f) + 1e-5f);
        int grow = m0 + row;
        int grr = grow < N ? grow : N - 1;
        const unsigned short* fA16 = (const unsigned short*)featA;
#pragma unroll
        for (int ci = 0; ci < 8; ++ci) {
            int cl = ci * 16 + q * 4;
            f32x4 a = acc2[ci];
            float4 gv = *(const float4*)(gw2 + cl);
            float4 bv = *(const float4*)(gb2 + cl);
            int2 rv = *(const int2*)(fA16 + (size_t)grr * 128 + cl);
            float y0 = fmaxf((a[0] - mean) * inv * gv.x + bv.x + bfl((unsigned)rv.x), 0.f);
            float y1 = fmaxf((a[1] - mean) * inv * gv.y + bv.y + bfh((unsigned)rv.x), 0.f);
            float y2 = fmaxf((a[2] - mean) * inv * gv.z + bv.z + bfl((unsigned)rv.y), 0.f);
            float y3 = fmaxf((a[3] - mean) * inv * gv.w + bv.w + bfh((unsigned)rv.y), 0.f);
            if (grow < N) {
                unsigned lo = (unsigned)f2bf(y0) | ((unsigned)f2bf(y1) << 16);
                unsigned hi = (unsigned)f2bf(y2) | ((unsigned)f2bf(y3) << 16);
                int2 pk; pk.x = (int)lo; pk.y = (int)hi;
                *(int2*)(featB + (size_t)grow * 128 + cl) = pk;
                if (LASTI) {
                    float4 o; o.x = y0; o.y = y1; o.z = y2; o.w = y3;
                    *(float4*)(featf + (size_t)grow * 128 + cl) = o;
                }
            }
        }
    }
}

// ---------------------------------------------------------------- launch
extern "C" void kernel_launch(void* const* d_in, const int* in_sizes, int n_in,
                              void* d_out, int out_size, void* d_ws, size_t ws_size,
                              hipStream_t stream) {
    const float* ctrs = (const float*)d_in[0];
    const float* feats = (const float*)d_in[1];
    const float* w_in1 = (const float*)d_in[2];
    const float* b_in1 = (const float*)d_in[3];
    const float* w_in2 = (const float*)d_in[4];
    const float* g_in = (const float*)d_in[5];
    const float* be_in = (const float*)d_in[6];
    const float* w_seg1 = (const float*)d_in[7];
    const float* b_seg1 = (const float*)d_in[8];
    const float* w_seg2 = (const float*)d_in[9];
    const float* g_seg = (const float*)d_in[10];
    const float* be_seg = (const float*)d_in[11];
    const float* ctr_w = (const float*)d_in[12];
    const float* pre_w = (const float*)d_in[13];
    const float* suc_w = (const float*)d_in[14];
    const float* left_w = (const float*)d_in[15];
    const float* right_w = (const float*)d_in[16];
    const float* norm_g = (const float*)d_in[17];
    const float* norm_b = (const float*)d_in[18];
    const float* ctr2_w = (const float*)d_in[19];
    const float* ctr2_g = (const float*)d_in[20];
    const float* ctr2_b = (const float*)d_in[21];
    const int* pre_u = (const int*)d_in[22];
    const int* pre_v = (const int*)d_in[23];
    const int* suc_u = (const int*)d_in[24];
    const int* suc_v = (const int*)d_in[25];
    const int* left_u = (const int*)d_in[26];
    const int* left_v = (const int*)d_in[27];
    const int* right_u = (const int*)d_in[28];
    const int* right_v = (const int*)d_in[29];

    const int N = in_sizes[0] / 2;
    const int E = in_sizes[22] / 6;
    const int E2 = in_sizes[26];
    const int Mtot = 12 * E + 2 * E2;

    char* ws = (char*)d_ws;
    size_t off = 0;
    auto alloc = [&](size_t b) { void* p = ws + off; off += (b + 255) & ~(size_t)255; return p; };

    unsigned short* Btw = (unsigned short*)alloc((size_t)66 * 16384 * 2);
    unsigned short* featb = (unsigned short*)alloc((size_t)N * 128 * 2);
    unsigned short* feat1b = (unsigned short*)alloc((size_t)N * 128 * 2);
    int* rowptrs = (int*)alloc((size_t)14 * (N + 1) * 4);
    int* cnt14 = (int*)alloc((size_t)14 * N * 4);
    int* bsum = (int*)alloc((size_t)14 * 128 * 4);
    int* edata = (int*)alloc((size_t)Mtot * 4);

    float* featf = (float*)d_out;

    wprep<<<dim3((66 * 16384 + 255) / 256), dim3(256), 0, stream>>>(
        w_in2, w_seg2, ctr_w, pre_w, suc_w, left_w, right_w, ctr2_w, Btw);

    // per-type CSR build (one pass count / fill, typed parallel scans)
    hipMemsetAsync(cnt14, 0, (size_t)14 * N * 4, stream);
    dim3 eg((Mtot + 255) / 256);
    edge_count14<<<eg, dim3(256), 0, stream>>>(
        pre_u, pre_v, suc_u, suc_v, left_u, left_v, right_u, right_v,
        E, E2, Mtot, N, cnt14);
    int nb = (N + 2047) / 2048;
    scanA2<<<dim3(nb, 14), dim3(256), 0, stream>>>(cnt14, N, rowptrs, bsum);
    scanB2<<<dim3(14), dim3(128), 0, stream>>>(bsum, nb, rowptrs, N);
    scanC2<<<dim3((N + 255) / 256, 14), dim3(256), 0, stream>>>(rowptrs, bsum, N);
    hipMemsetAsync(cnt14, 0, (size_t)14 * N * 4, stream);
    edge_fill14<<<eg, dim3(256), 0, stream>>>(
        pre_u, pre_v, suc_u, suc_v, left_u, left_v, right_u, right_v,
        E, E2, Mtot, N, rowptrs, cnt14, edata);

    // encoders -> featb (= feat^0)
    enc<<<dim3((N * 128 + 255) / 256), dim3(256), 0, stream>>>(
        ctrs, feats, w_in1, b_in1, w_seg1, b_seg1, feat1b, featb, N);
    const int gblk = (N + 127) / 128;
    gemm128<MODE_GN><<<dim3(gblk), dim3(256), 0, stream>>>(
        feat1b, Btw, N, nullptr, nullptr, feat1b, g_in, be_in);
    gemm128<MODE_GNADD><<<dim3(gblk), dim3(256), 0, stream>>>(
        featb, Btw + 16384, N, feat1b, nullptr, featb, g_seg, be_seg);

    // fused iterations (ping-pong featb <-> feat1b)
    const int fblk = (N + 63) / 64;
    for (int i = 0; i < 4; ++i) {
        const unsigned* fA = (const unsigned*)((i & 1) ? feat1b : featb);
        unsigned short* fB = (i & 1) ? featb : feat1b;
        const unsigned short* Bt15 = Btw + (size_t)(2 + i * 15) * 16384;
        const unsigned short* Bc2 = Btw + (size_t)(62 + i) * 16384;
        if (i == 3)
            fuse_gemm<1><<<dim3(fblk), dim3(256), 0, stream>>>(
                fA, fB, featf, Bt15, Bc2, rowptrs, edata, N, E, E2,
                norm_g + i * 128, norm_b + i * 128, ctr2_g + i * 128, ctr2_b + i * 128);
        else
            fuse_gemm<0><<<dim3(fblk), dim3(256), 0, stream>>>(
                fA, fB, featf, Bt15, Bc2, rowptrs, edata, N, E, E2,
                norm_g + i * 128, norm_b + i * 128, ctr2_g + i * 128, ctr2_b + i * 128);
    }
}

// Round 6
// 3776.361 us; speedup vs baseline: 2.2065x; 2.2065x over previous
//
#include <hip/hip_runtime.h>

typedef __attribute__((ext_vector_type(8))) short bf16x8;
typedef __attribute__((ext_vector_type(4))) float f32x4;

#define DEV static __device__ __forceinline__

DEV unsigned short f2bf(float f) {
    union { float f; unsigned u; } a; a.f = f;
    unsigned r = a.u + 0x7FFFu + ((a.u >> 16) & 1u);
    return (unsigned short)(r >> 16);
}
DEV float bfl(unsigned u) { union { unsigned u; float f; } a; a.u = u << 16; return a.f; }
DEV float bfh(unsigned u) { union { unsigned u; float f; } a; a.u = u & 0xFFFF0000u; return a.f; }

// ---------------------------------------------------------------- weight prep
__global__ void wprep(const float* __restrict__ w_in2, const float* __restrict__ w_seg2,
                      const float* __restrict__ ctr_w, const float* __restrict__ pre_w,
                      const float* __restrict__ suc_w, const float* __restrict__ left_w,
                      const float* __restrict__ right_w, const float* __restrict__ ctr2_w,
                      unsigned short* __restrict__ Btw) {
    int idx = blockIdx.x * 256 + threadIdx.x;
    if (idx >= 66 * 16384) return;
    int p = idx >> 14, within = idx & 16383;
    int c = within >> 7, k = within & 127;
    const float* src;
    if (p == 0) src = w_in2;
    else if (p == 1) src = w_seg2;
    else if (p < 62) {
        int pi = p - 2; int i = pi / 15, t = pi % 15;
        if (t == 0) src = ctr_w + i * 16384;
        else if (t < 7) src = pre_w + (i * 6 + (t - 1)) * 16384;
        else if (t < 13) src = suc_w + (i * 6 + (t - 7)) * 16384;
        else if (t == 13) src = left_w + i * 16384;
        else src = right_w + i * 16384;
    } else src = ctr2_w + (p - 62) * 16384;
    Btw[idx] = f2bf(src[k * 128 + c]);
}

// ---------------------------------------------------------------- per-type CSR build
DEV int edge_decode(int e, int E, int E2,
                    const int* pre_u, const int* pre_v, const int* suc_u, const int* suc_v,
                    const int* left_u, const int* left_v, const int* right_u, const int* right_v,
                    int* u, int* v) {
    if (e < 12 * E) {
        int s = e / E, off = e - s * E;
        if (s < 6) { *u = pre_u[s * E + off]; *v = pre_v[s * E + off]; }
        else { *u = suc_u[(s - 6) * E + off]; *v = suc_v[(s - 6) * E + off]; }
        return 1 + s;
    }
    int e2 = e - 12 * E;
    if (e2 < E2) { *u = left_u[e2]; *v = left_v[e2]; return 13; }
    *u = right_u[e2 - E2]; *v = right_v[e2 - E2]; return 14;
}

__global__ void edge_count14(const int* __restrict__ pre_u, const int* __restrict__ pre_v,
                             const int* __restrict__ suc_u, const int* __restrict__ suc_v,
                             const int* __restrict__ left_u, const int* __restrict__ left_v,
                             const int* __restrict__ right_u, const int* __restrict__ right_v,
                             int E, int E2, int Mtot, int N, int* __restrict__ cnt14) {
    int e = blockIdx.x * 256 + threadIdx.x;
    if (e >= Mtot) return;
    int u, v;
    int t = edge_decode(e, E, E2, pre_u, pre_v, suc_u, suc_v, left_u, left_v, right_u, right_v, &u, &v);
    atomicAdd(&cnt14[(size_t)(t - 1) * N + u], 1);
}

__global__ void edge_fill14(const int* __restrict__ pre_u, const int* __restrict__ pre_v,
                            const int* __restrict__ suc_u, const int* __restrict__ suc_v,
                            const int* __restrict__ left_u, const int* __restrict__ left_v,
                            const int* __restrict__ right_u, const int* __restrict__ right_v,
                            int E, int E2, int Mtot, int N,
                            const int* __restrict__ rowptrs, int* __restrict__ cur,
                            int* __restrict__ edata) {
    int e = blockIdx.x * 256 + threadIdx.x;
    if (e >= Mtot) return;
    int u, v;
    int t = edge_decode(e, E, E2, pre_u, pre_v, suc_u, suc_v, left_u, left_v, right_u, right_v, &u, &v);
    int tt = t - 1;
    int pos = atomicAdd(&cur[(size_t)tt * N + u], 1);
    size_t base = (tt <= 11) ? (size_t)tt * E : (size_t)12 * E + (size_t)(tt - 12) * E2;
    edata[base + rowptrs[(size_t)tt * (N + 1) + u] + pos] = ((u & 63) << 18) | v;
}

__global__ void scanA2(const int* __restrict__ cnt14, int N, int* __restrict__ rowptrs,
                       int* __restrict__ bsum) {
    const int* cnt = cnt14 + (size_t)blockIdx.y * N;
    int* rowptr = rowptrs + (size_t)blockIdx.y * (N + 1);
    int* bs = bsum + blockIdx.y * 128;
    __shared__ int lds[256];
    int tid = threadIdx.x;
    int base = blockIdx.x * 2048 + tid * 8;
    int v[8]; int s = 0;
#pragma unroll
    for (int j = 0; j < 8; ++j) { int i = base + j; v[j] = (i < N) ? cnt[i] : 0; s += v[j]; }
    lds[tid] = s; __syncthreads();
    for (int d = 1; d < 256; d <<= 1) {
        int t2 = (tid >= d) ? lds[tid - d] : 0;
        __syncthreads();
        lds[tid] += t2;
        __syncthreads();
    }
    int excl = lds[tid] - s;
    if (tid == 255) bs[blockIdx.x] = lds[255];
    int run = excl;
#pragma unroll
    for (int j = 0; j < 8; ++j) { int i = base + j; if (i < N) rowptr[i] = run; run += v[j]; }
}

__global__ void scanB2(int* __restrict__ bsum, int nb, int* __restrict__ rowptrs, int N) {
    int* bs = bsum + blockIdx.x * 128;
    __shared__ int lds[128];
    int tid = threadIdx.x;
    int v = (tid < nb) ? bs[tid] : 0;
    lds[tid] = v; __syncthreads();
    for (int d = 1; d < 128; d <<= 1) {
        int t2 = (tid >= d) ? lds[tid - d] : 0;
        __syncthreads();
        lds[tid] += t2;
        __syncthreads();
    }
    if (tid < nb) bs[tid] = lds[tid] - v;
    if (tid == 127) rowptrs[(size_t)blockIdx.x * (N + 1) + N] = lds[127];
}

__global__ void scanC2(int* __restrict__ rowptrs, const int* __restrict__ bsum, int N) {
    int i = blockIdx.x * 256 + threadIdx.x;
    if (i < N) rowptrs[(size_t)blockIdx.y * (N + 1) + i] += bsum[blockIdx.y * 128 + (i >> 11)];
}

// ---------------------------------------------------------------- encoders (first linear+relu)
__global__ void enc(const float* __restrict__ ctrs, const float* __restrict__ feats,
                    const float* __restrict__ w_in1, const float* __restrict__ b_in1,
                    const float* __restrict__ w_seg1, const float* __restrict__ b_seg1,
                    unsigned short* __restrict__ h_in, unsigned short* __restrict__ h_seg, int N) {
    int idx = blockIdx.x * 256 + threadIdx.x;
    if (idx >= N * 128) return;
    int n = idx >> 7, c = idx & 127;
    float x0 = ctrs[2 * n], x1 = ctrs[2 * n + 1];
    float h = fmaxf(x0 * w_in1[c] + x1 * w_in1[128 + c] + b_in1[c], 0.f);
    h_in[idx] = f2bf(h);
    x0 = feats[2 * n]; x1 = feats[2 * n + 1];
    h = fmaxf(x0 * w_seg1[c] + x1 * w_seg1[128 + c] + b_seg1[c], 0.f);
    h_seg[idx] = f2bf(h);
}

// ---------------------------------------------------------------- encoder GEMM (single plane)
enum { MODE_GN = 1, MODE_GNADD = 2 };

template <int MODE>
__global__ __launch_bounds__(256, 2) void gemm128(
    const unsigned short* __restrict__ A,
    const unsigned short* __restrict__ Bt,
    int M,
    const unsigned short* __restrict__ resb,
    float* __restrict__ outf,
    unsigned short* __restrict__ outb,
    const float* __restrict__ gw, const float* __restrict__ gb) {
    __shared__ char Asm[32768];
    __shared__ char Bsm[32768];
    const int tid = threadIdx.x;
    const int wv = tid >> 6, ln = tid & 63;
    const int q = ln >> 4, r = ln & 15;
    const int m0 = blockIdx.x * 128;

#pragma unroll
    for (int s = 0; s < 8; ++s) {
        int f = s * 256 + tid;
        int row = f >> 4, ck = f & 15;
        int grow = m0 + row; if (grow >= M) grow = M - 1;
        int4 v = *(const int4*)(A + (size_t)grow * 128 + ck * 8);
        *(int4*)(Asm + row * 256 + ((ck * 16) ^ ((row & 7) << 4))) = v;
    }
#pragma unroll
    for (int s = 0; s < 8; ++s) {
        int f = s * 256 + tid;
        int c = f >> 4, ck = f & 15;
        int4 v = *(const int4*)(Bt + c * 128 + ck * 8);
        *(int4*)(Bsm + c * 256 + ((ck * 16) ^ ((c & 7) << 4))) = v;
    }
    __syncthreads();

    f32x4 acc[2][8];
#pragma unroll
    for (int fj = 0; fj < 2; ++fj)
#pragma unroll
        for (int ci = 0; ci < 8; ++ci) acc[fj][ci] = (f32x4)(0.f);

#pragma unroll
    for (int k0 = 0; k0 < 128; k0 += 32) {
        int kb = k0 * 2 + q * 16;
        bf16x8 wf[8], ff[2];
#pragma unroll
        for (int ci = 0; ci < 8; ++ci) {
            int c = ci * 16 + r;
            wf[ci] = *(const bf16x8*)(Bsm + c * 256 + (kb ^ ((c & 7) << 4)));
        }
#pragma unroll
        for (int fj = 0; fj < 2; ++fj) {
            int row = wv * 32 + fj * 16 + r;
            ff[fj] = *(const bf16x8*)(Asm + row * 256 + (kb ^ ((row & 7) << 4)));
        }
#pragma unroll
        for (int fj = 0; fj < 2; ++fj)
#pragma unroll
            for (int ci = 0; ci < 8; ++ci)
                acc[fj][ci] = __builtin_amdgcn_mfma_f32_16x16x32_bf16(wf[ci], ff[fj], acc[fj][ci], 0, 0, 0);
    }

#pragma unroll
    for (int fj = 0; fj < 2; ++fj) {
        float s = 0.f;
#pragma unroll
        for (int ci = 0; ci < 8; ++ci) {
            f32x4 a = acc[fj][ci];
            s += a[0] + a[1] + a[2] + a[3];
        }
        s += __shfl_xor(s, 16); s += __shfl_xor(s, 32);
        float mean = s * (1.f / 128.f);
        float vs = 0.f;
#pragma unroll
        for (int ci = 0; ci < 8; ++ci) {
            f32x4 a = acc[fj][ci];
#pragma unroll
            for (int j = 0; j < 4; ++j) { float d = a[j] - mean; vs += d * d; }
        }
        vs += __shfl_xor(vs, 16); vs += __shfl_xor(vs, 32);
        float inv = rsqrtf(vs * (1.f / 128.f) + 1e-5f);
        int row = m0 + wv * 32 + fj * 16 + r;
        if (row < M) {
#pragma unroll
            for (int ci = 0; ci < 8; ++ci) {
                int col = ci * 16 + q * 4;
                f32x4 a = acc[fj][ci];
                float4 gv = *(const float4*)(gw + col);
                float4 bv = *(const float4*)(gb + col);
                float y0 = (a[0] - mean) * inv * gv.x + bv.x;
                float y1 = (a[1] - mean) * inv * gv.y + bv.y;
                float y2 = (a[2] - mean) * inv * gv.z + bv.z;
                float y3 = (a[3] - mean) * inv * gv.w + bv.w;
                if (MODE == MODE_GNADD) {
                    int2 rv = *(const int2*)(resb + (size_t)row * 128 + col);
                    y0 = fmaxf(y0 + bfl((unsigned)rv.x), 0.f);
                    y1 = fmaxf(y1 + bfh((unsigned)rv.x), 0.f);
                    y2 = fmaxf(y2 + bfl((unsigned)rv.y), 0.f);
                    y3 = fmaxf(y3 + bfh((unsigned)rv.y), 0.f);
                    if (outf) {
                        float4 o; o.x = y0; o.y = y1; o.z = y2; o.w = y3;
                        *(float4*)(outf + (size_t)row * 128 + col) = o;
                    }
                }
                unsigned lo = (unsigned)f2bf(y0) | ((unsigned)f2bf(y1) << 16);
                unsigned hi = (unsigned)f2bf(y2) | ((unsigned)f2bf(y3) << 16);
                int2 pk; pk.x = (int)lo; pk.y = (int)hi;
                *(int2*)(outb + (size_t)row * 128 + col) = pk;
            }
        }
    }
}

// ---------------------------------------------------------------- fused iteration kernel
// Wave-owned rows: wave wv owns local rows [wv*16, wv*16+16) == nodes g0..g0+15.
// Per type: slot-k register accumulation (lane = 2 cols) from L3-resident feat
// rows, ONE LDS write per row (no atomics), then MFMA acc += agg @ W_t using
// only the wave's own rows. Epilogues: GN+ReLU -> P(LDS) -> P@ctr2 -> GN +
// residual + ReLU -> featB (+featf on last iter).
template <int LASTI>
__global__ __launch_bounds__(256, 2) void fuse_gemm(
    const unsigned* __restrict__ featA,       // [N][64] packed 2xbf16 words
    unsigned short* __restrict__ featB,       // [N][128] bf16 out
    float* __restrict__ featf,                // [N][128] f32 out (LASTI)
    const unsigned short* __restrict__ Bt15,  // 15 planes
    const unsigned short* __restrict__ Bc2,   // ctr2 plane
    const int* __restrict__ rowptrs,          // 14*(N+1)
    const int* __restrict__ edata,
    int N, int E, int E2,
    const float* __restrict__ gw1, const float* __restrict__ gb1,
    const float* __restrict__ gw2, const float* __restrict__ gb2) {
    __shared__ float aggF[64 * 128];   // 32KB, XOR-swizzled rows
    __shared__ char Bsm[32768];
    const int tid = threadIdx.x;
    const int wv = tid >> 6, ln = tid & 63;
    const int q = ln >> 4, r = ln & 15;
    const int m0 = blockIdx.x * 64;
    const int row = wv * 16 + r;
    const int swR = (row & 7) << 2;
    const int swB = (row & 7) << 4;
    const int g0 = m0 + wv * 16;

    f32x4 acc[8];
#pragma unroll
    for (int ci = 0; ci < 8; ++ci) acc[ci] = (f32x4)(0.f);

    for (int t = 0; t < 15; ++t) {
        __syncthreads();  // previous MFMA done with Bsm
        // stage W_t
        {
            const unsigned short* Bp = Bt15 + (size_t)t * 16384;
#pragma unroll
            for (int s = 0; s < 8; ++s) {
                int f = s * 256 + tid;
                int c = f >> 4, ck = f & 15;
                int4 v = *(const int4*)(Bp + c * 128 + ck * 8);
                *(int4*)(Bsm + c * 256 + ((ck * 16) ^ ((c & 7) << 4))) = v;
            }
        }
        // build this wave's 16 aggF rows
        if (t == 0) {
#pragma unroll
            for (int k = 0; k < 16; ++k) {
                int g = g0 + k; if (g >= N) g = N - 1;
                unsigned p = featA[(size_t)g * 64 + ln];
                int lr = wv * 16 + k;
                int idx = lr * 128 + ((2 * ln) ^ ((lr & 7) << 2));
                aggF[idx] = bfl(p);
                aggF[idx + 1] = bfh(p);
            }
        } else {
            int tt = t - 1;
            size_t base = (tt <= 11) ? (size_t)tt * E : (size_t)12 * E + (size_t)(tt - 12) * E2;
            const int* rp = rowptrs + (size_t)tt * (N + 1);
            const int* ed = edata + base;
            int nidx = g0 + (ln & 15);
            if (nidx >= N) nidx = N - 1;
            int sA = rp[nidx];
            int eA = rp[nidx + 1];
            int sk[16], dk[16];
            int maxd = 0;
#pragma unroll
            for (int k = 0; k < 16; ++k) {
                sk[k] = __builtin_amdgcn_readlane(sA, k);
                int ek = __builtin_amdgcn_readlane(eA, k);
                dk[k] = ek - sk[k];
                maxd = dk[k] > maxd ? dk[k] : maxd;
            }
            float f0[16], f1[16];
#pragma unroll
            for (int k = 0; k < 16; ++k) { f0[k] = 0.f; f1[k] = 0.f; }
            for (int d = 0; d < maxd; ++d) {
#pragma unroll
                for (int k = 0; k < 16; ++k) {
                    if (d < dk[k]) {
                        int w = ed[sk[k] + d];
                        unsigned p = featA[(size_t)(unsigned)(w & 0x3FFFF) * 64 + ln];
                        f0[k] += bfl(p);
                        f1[k] += bfh(p);
                    }
                }
            }
#pragma unroll
            for (int k = 0; k < 16; ++k) {
                int lr = wv * 16 + k;
                int idx = lr * 128 + ((2 * ln) ^ ((lr & 7) << 2));
                aggF[idx] = f0[k];
                aggF[idx + 1] = f1[k];
            }
        }
        __syncthreads();  // Bsm staged (aggF rows are wave-own)
        // MFMA accumulate: acc += agg @ W_t
#pragma unroll
        for (int k0 = 0; k0 < 128; k0 += 32) {
            int c0 = k0 + q * 8;
            f32x4 fa = *(const f32x4*)(aggF + row * 128 + (c0 ^ swR));
            f32x4 fb = *(const f32x4*)(aggF + row * 128 + ((c0 + 4) ^ swR));
            bf16x8 ff;
            ff[0] = (short)f2bf(fa[0]); ff[1] = (short)f2bf(fa[1]);
            ff[2] = (short)f2bf(fa[2]); ff[3] = (short)f2bf(fa[3]);
            ff[4] = (short)f2bf(fb[0]); ff[5] = (short)f2bf(fb[1]);
            ff[6] = (short)f2bf(fb[2]); ff[7] = (short)f2bf(fb[3]);
            int kb = k0 * 2 + q * 16;
#pragma unroll
            for (int ci = 0; ci < 8; ++ci) {
                int c = ci * 16 + r;
                bf16x8 wf = *(const bf16x8*)(Bsm + c * 256 + (kb ^ ((c & 7) << 4)));
                acc[ci] = __builtin_amdgcn_mfma_f32_16x16x32_bf16(wf, ff, acc[ci], 0, 0, 0);
            }
        }
    }

    // ---- epilogue 1: GN(norm) + ReLU -> py (bf16 packed)
    int2 py[8];
    {
        float s = 0.f;
#pragma unroll
        for (int ci = 0; ci < 8; ++ci) {
            f32x4 a = acc[ci];
            s += a[0] + a[1] + a[2] + a[3];
        }
        s += __shfl_xor(s, 16); s += __shfl_xor(s, 32);
        float mean = s * (1.f / 128.f);
        float vs = 0.f;
#pragma unroll
        for (int ci = 0; ci < 8; ++ci) {
            f32x4 a = acc[ci];
#pragma unroll
            for (int j = 0; j < 4; ++j) { float d = a[j] - mean; vs += d * d; }
        }
        vs += __shfl_xor(vs, 16); vs += __shfl_xor(vs, 32);
        float inv = rsqrtf(vs * (1.f / 128.f) + 1e-5f);
#pragma unroll
        for (int ci = 0; ci < 8; ++ci) {
            int cl = ci * 16 + q * 4;
            f32x4 a = acc[ci];
            float4 gv = *(const float4*)(gw1 + cl);
            float4 bv = *(const float4*)(gb1 + cl);
            float y0 = fmaxf((a[0] - mean) * inv * gv.x + bv.x, 0.f);
            float y1 = fmaxf((a[1] - mean) * inv * gv.y + bv.y, 0.f);
            float y2 = fmaxf((a[2] - mean) * inv * gv.z + bv.z, 0.f);
            float y3 = fmaxf((a[3] - mean) * inv * gv.w + bv.w, 0.f);
            py[ci].x = (int)((unsigned)f2bf(y0) | ((unsigned)f2bf(y1) << 16));
            py[ci].y = (int)((unsigned)f2bf(y2) | ((unsigned)f2bf(y3) << 16));
        }
    }
    __syncthreads();  // all waves done reading aggF/Bsm
    // store P (bf16 tile) + stage ctr2 weights
    char* P = (char*)aggF;
#pragma unroll
    for (int ci = 0; ci < 8; ++ci)
        *(int2*)(P + row * 256 + ((ci * 32 + q * 8) ^ swB)) = py[ci];
#pragma unroll
    for (int s = 0; s < 8; ++s) {
        int f = s * 256 + tid;
        int c = f >> 4, ck = f & 15;
        int4 v = *(const int4*)(Bc2 + c * 128 + ck * 8);
        *(int4*)(Bsm + c * 256 + ((ck * 16) ^ ((c & 7) << 4))) = v;
    }
    __syncthreads();

    // ---- second GEMM: acc2 = P @ ctr2
    f32x4 acc2[8];
#pragma unroll
    for (int ci = 0; ci < 8; ++ci) acc2[ci] = (f32x4)(0.f);
#pragma unroll
    for (int k0 = 0; k0 < 128; k0 += 32) {
        int kb = k0 * 2 + q * 16;
        bf16x8 ff = *(const bf16x8*)(P + row * 256 + (kb ^ swB));
#pragma unroll
        for (int ci = 0; ci < 8; ++ci) {
            int c = ci * 16 + r;
            bf16x8 wf = *(const bf16x8*)(Bsm + c * 256 + (kb ^ ((c & 7) << 4)));
            acc2[ci] = __builtin_amdgcn_mfma_f32_16x16x32_bf16(wf, ff, acc2[ci], 0, 0, 0);
        }
    }

    // ---- epilogue 2: GN(ctr2) + residual + ReLU -> featB (+featf)
    {
        float s = 0.f;
#pragma unroll
        for (int ci = 0; ci < 8; ++ci) {
            f32x4 a = acc2[ci];
            s += a[0] + a[1] + a[2] + a[3];
        }
        s += __shfl_xor(s, 16); s += __shfl_xor(s, 32);
        float mean = s * (1.f / 128.f);
        float vs = 0.f;
#pragma unroll
        for (int ci = 0; ci < 8; ++ci) {
            f32x4 a = acc2[ci];
#pragma unroll
            for (int j = 0; j < 4; ++j) { float d = a[j] - mean; vs += d * d; }
        }
        vs += __shfl_xor(vs, 16); vs += __shfl_xor(vs, 32);
        float inv = rsqrtf(vs * (1.f / 128.f) + 1e-5f);
        int grow = m0 + row;
        int grr = grow < N ? grow : N - 1;
        const unsigned short* fA16 = (const unsigned short*)featA;
#pragma unroll
        for (int ci = 0; ci < 8; ++ci) {
            int cl = ci * 16 + q * 4;
            f32x4 a = acc2[ci];
            float4 gv = *(const float4*)(gw2 + cl);
            float4 bv = *(const float4*)(gb2 + cl);
            int2 rv = *(const int2*)(fA16 + (size_t)grr * 128 + cl);
            float y0 = fmaxf((a[0] - mean) * inv * gv.x + bv.x + bfl((unsigned)rv.x), 0.f);
            float y1 = fmaxf((a[1] - mean) * inv * gv.y + bv.y + bfh((unsigned)rv.x), 0.f);
            float y2 = fmaxf((a[2] - mean) * inv * gv.z + bv.z + bfl((unsigned)rv.y), 0.f);
            float y3 = fmaxf((a[3] - mean) * inv * gv.w + bv.w + bfh((unsigned)rv.y), 0.f);
            if (grow < N) {
                unsigned lo = (unsigned)f2bf(y0) | ((unsigned)f2bf(y1) << 16);
                unsigned hi = (unsigned)f2bf(y2) | ((unsigned)f2bf(y3) << 16);
                int2 pk; pk.x = (int)lo; pk.y = (int)hi;
                *(int2*)(featB + (size_t)grow * 128 + cl) = pk;
                if (LASTI) {
                    float4 o; o.x = y0; o.y = y1; o.z = y2; o.w = y3;
                    *(float4*)(featf + (size_t)grow * 128 + cl) = o;
                }
            }
        }
    }
}

// ---------------------------------------------------------------- launch
extern "C" void kernel_launch(void* const* d_in, const int* in_sizes, int n_in,
                              void* d_out, int out_size, void* d_ws, size_t ws_size,
                              hipStream_t stream) {
    const float* ctrs = (const float*)d_in[0];
    const float* feats = (const float*)d_in[1];
    const float* w_in1 = (const float*)d_in[2];
    const float* b_in1 = (const float*)d_in[3];
    const float* w_in2 = (const float*)d_in[4];
    const float* g_in = (const float*)d_in[5];
    const float* be_in = (const float*)d_in[6];
    const float* w_seg1 = (const float*)d_in[7];
    const float* b_seg1 = (const float*)d_in[8];
    const float* w_seg2 = (const float*)d_in[9];
    const float* g_seg = (const float*)d_in[10];
    const float* be_seg = (const float*)d_in[11];
    const float* ctr_w = (const float*)d_in[12];
    const float* pre_w = (const float*)d_in[13];
    const float* suc_w = (const float*)d_in[14];
    const float* left_w = (const float*)d_in[15];
    const float* right_w = (const float*)d_in[16];
    const float* norm_g = (const float*)d_in[17];
    const float* norm_b = (const float*)d_in[18];
    const float* ctr2_w = (const float*)d_in[19];
    const float* ctr2_g = (const float*)d_in[20];
    const float* ctr2_b = (const float*)d_in[21];
    const int* pre_u = (const int*)d_in[22];
    const int* pre_v = (const int*)d_in[23];
    const int* suc_u = (const int*)d_in[24];
    const int* suc_v = (const int*)d_in[25];
    const int* left_u = (const int*)d_in[26];
    const int* left_v = (const int*)d_in[27];
    const int* right_u = (const int*)d_in[28];
    const int* right_v = (const int*)d_in[29];

    const int N = in_sizes[0] / 2;
    const int E = in_sizes[22] / 6;
    const int E2 = in_sizes[26];
    const int Mtot = 12 * E + 2 * E2;

    char* ws = (char*)d_ws;
    size_t off = 0;
    auto alloc = [&](size_t b) { void* p = ws + off; off += (b + 255) & ~(size_t)255; return p; };

    unsigned short* Btw = (unsigned short*)alloc((size_t)66 * 16384 * 2);
    unsigned short* featb = (unsigned short*)alloc((size_t)N * 128 * 2);
    unsigned short* feat1b = (unsigned short*)alloc((size_t)N * 128 * 2);
    int* rowptrs = (int*)alloc((size_t)14 * (N + 1) * 4);
    int* cnt14 = (int*)alloc((size_t)14 * N * 4);
    int* bsum = (int*)alloc((size_t)14 * 128 * 4);
    int* edata = (int*)alloc((size_t)Mtot * 4);

    float* featf = (float*)d_out;

    wprep<<<dim3((66 * 16384 + 255) / 256), dim3(256), 0, stream>>>(
        w_in2, w_seg2, ctr_w, pre_w, suc_w, left_w, right_w, ctr2_w, Btw);

    // per-type CSR build
    hipMemsetAsync(cnt14, 0, (size_t)14 * N * 4, stream);
    dim3 eg((Mtot + 255) / 256);
    edge_count14<<<eg, dim3(256), 0, stream>>>(
        pre_u, pre_v, suc_u, suc_v, left_u, left_v, right_u, right_v,
        E, E2, Mtot, N, cnt14);
    int nb = (N + 2047) / 2048;
    scanA2<<<dim3(nb, 14), dim3(256), 0, stream>>>(cnt14, N, rowptrs, bsum);
    scanB2<<<dim3(14), dim3(128), 0, stream>>>(bsum, nb, rowptrs, N);
    scanC2<<<dim3((N + 255) / 256, 14), dim3(256), 0, stream>>>(rowptrs, bsum, N);
    hipMemsetAsync(cnt14, 0, (size_t)14 * N * 4, stream);
    edge_fill14<<<eg, dim3(256), 0, stream>>>(
        pre_u, pre_v, suc_u, suc_v, left_u, left_v, right_u, right_v,
        E, E2, Mtot, N, rowptrs, cnt14, edata);

    // encoders -> featb (= feat^0)
    enc<<<dim3((N * 128 + 255) / 256), dim3(256), 0, stream>>>(
        ctrs, feats, w_in1, b_in1, w_seg1, b_seg1, feat1b, featb, N);
    const int gblk = (N + 127) / 128;
    gemm128<MODE_GN><<<dim3(gblk), dim3(256), 0, stream>>>(
        feat1b, Btw, N, nullptr, nullptr, feat1b, g_in, be_in);
    gemm128<MODE_GNADD><<<dim3(gblk), dim3(256), 0, stream>>>(
        featb, Btw + 16384, N, feat1b, nullptr, featb, g_seg, be_seg);

    // fused iterations (ping-pong featb <-> feat1b)
    const int fblk = (N + 63) / 64;
    for (int i = 0; i < 4; ++i) {
        const unsigned* fA = (const unsigned*)((i & 1) ? feat1b : featb);
        unsigned short* fB = (i & 1) ? featb : feat1b;
        const unsigned short* Bt15 = Btw + (size_t)(2 + i * 15) * 16384;
        const unsigned short* Bc2 = Btw + (size_t)(62 + i) * 16384;
        if (i == 3)
            fuse_gemm<1><<<dim3(fblk), dim3(256), 0, stream>>>(
                fA, fB, featf, Bt15, Bc2, rowptrs, edata, N, E, E2,
                norm_g + i * 128, norm_b + i * 128, ctr2_g + i * 128, ctr2_b + i * 128);
        else
            fuse_gemm<0><<<dim3(fblk), dim3(256), 0, stream>>>(
                fA, fB, featf, Bt15, Bc2, rowptrs, edata, N, E, E2,
                norm_g + i * 128, norm_b + i * 128, ctr2_g + i * 128, ctr2_b + i * 128);
    }
}

// Round 7
// 1950.798 us; speedup vs baseline: 4.2713x; 1.9358x over previous
//
#include <hip/hip_runtime.h>

typedef __attribute__((ext_vector_type(8))) short bf16x8;
typedef __attribute__((ext_vector_type(4))) float f32x4;

#define DEV static __device__ __forceinline__

DEV unsigned short f2bf(float f) {
    union { float f; unsigned u; } a; a.f = f;
    unsigned r = a.u + 0x7FFFu + ((a.u >> 16) & 1u);
    return (unsigned short)(r >> 16);
}
DEV float bfl(unsigned u) { union { unsigned u; float f; } a; a.u = u << 16; return a.f; }
DEV float bfh(unsigned u) { union { unsigned u; float f; } a; a.u = u & 0xFFFF0000u; return a.f; }

// ---------------------------------------------------------------- weight prep
__global__ void wprep(const float* __restrict__ w_in2, const float* __restrict__ w_seg2,
                      const float* __restrict__ ctr_w, const float* __restrict__ pre_w,
                      const float* __restrict__ suc_w, const float* __restrict__ left_w,
                      const float* __restrict__ right_w, const float* __restrict__ ctr2_w,
                      unsigned short* __restrict__ Btw) {
    int idx = blockIdx.x * 256 + threadIdx.x;
    if (idx >= 66 * 16384) return;
    int p = idx >> 14, within = idx & 16383;
    int c = within >> 7, k = within & 127;
    const float* src;
    if (p == 0) src = w_in2;
    else if (p == 1) src = w_seg2;
    else if (p < 62) {
        int pi = p - 2; int i = pi / 15, t = pi % 15;
        if (t == 0) src = ctr_w + i * 16384;
        else if (t < 7) src = pre_w + (i * 6 + (t - 1)) * 16384;
        else if (t < 13) src = suc_w + (i * 6 + (t - 7)) * 16384;
        else if (t == 13) src = left_w + i * 16384;
        else src = right_w + i * 16384;
    } else src = ctr2_w + (p - 62) * 16384;
    Btw[idx] = f2bf(src[k * 128 + c]);
}

// ---------------------------------------------------------------- per-type CSR build
DEV int edge_decode(int e, int E, int E2,
                    const int* pre_u, const int* pre_v, const int* suc_u, const int* suc_v,
                    const int* left_u, const int* left_v, const int* right_u, const int* right_v,
                    int* u, int* v) {
    if (e < 12 * E) {
        int s = e / E, off = e - s * E;
        if (s < 6) { *u = pre_u[s * E + off]; *v = pre_v[s * E + off]; }
        else { *u = suc_u[(s - 6) * E + off]; *v = suc_v[(s - 6) * E + off]; }
        return 1 + s;
    }
    int e2 = e - 12 * E;
    if (e2 < E2) { *u = left_u[e2]; *v = left_v[e2]; return 13; }
    *u = right_u[e2 - E2]; *v = right_v[e2 - E2]; return 14;
}

__global__ void edge_count14(const int* __restrict__ pre_u, const int* __restrict__ pre_v,
                             const int* __restrict__ suc_u, const int* __restrict__ suc_v,
                             const int* __restrict__ left_u, const int* __restrict__ left_v,
                             const int* __restrict__ right_u, const int* __restrict__ right_v,
                             int E, int E2, int Mtot, int N, int* __restrict__ cnt14) {
    int e = blockIdx.x * 256 + threadIdx.x;
    if (e >= Mtot) return;
    int u, v;
    int t = edge_decode(e, E, E2, pre_u, pre_v, suc_u, suc_v, left_u, left_v, right_u, right_v, &u, &v);
    atomicAdd(&cnt14[(size_t)(t - 1) * N + u], 1);
}

__global__ void edge_fill14(const int* __restrict__ pre_u, const int* __restrict__ pre_v,
                            const int* __restrict__ suc_u, const int* __restrict__ suc_v,
                            const int* __restrict__ left_u, const int* __restrict__ left_v,
                            const int* __restrict__ right_u, const int* __restrict__ right_v,
                            int E, int E2, int Mtot, int N,
                            const int* __restrict__ rowptrs, int* __restrict__ cur,
                            int* __restrict__ edata) {
    int e = blockIdx.x * 256 + threadIdx.x;
    if (e >= Mtot) return;
    int u, v;
    int t = edge_decode(e, E, E2, pre_u, pre_v, suc_u, suc_v, left_u, left_v, right_u, right_v, &u, &v);
    int tt = t - 1;
    int pos = atomicAdd(&cur[(size_t)tt * N + u], 1);
    size_t base = (tt <= 11) ? (size_t)tt * E : (size_t)12 * E + (size_t)(tt - 12) * E2;
    edata[base + rowptrs[(size_t)tt * (N + 1) + u] + pos] = ((u & 63) << 18) | v;
}

__global__ void scanA2(const int* __restrict__ cnt14, int N, int* __restrict__ rowptrs,
                       int* __restrict__ bsum) {
    const int* cnt = cnt14 + (size_t)blockIdx.y * N;
    int* rowptr = rowptrs + (size_t)blockIdx.y * (N + 1);
    int* bs = bsum + blockIdx.y * 128;
    __shared__ int lds[256];
    int tid = threadIdx.x;
    int base = blockIdx.x * 2048 + tid * 8;
    int v[8]; int s = 0;
#pragma unroll
    for (int j = 0; j < 8; ++j) { int i = base + j; v[j] = (i < N) ? cnt[i] : 0; s += v[j]; }
    lds[tid] = s; __syncthreads();
    for (int d = 1; d < 256; d <<= 1) {
        int t2 = (tid >= d) ? lds[tid - d] : 0;
        __syncthreads();
        lds[tid] += t2;
        __syncthreads();
    }
    int excl = lds[tid] - s;
    if (tid == 255) bs[blockIdx.x] = lds[255];
    int run = excl;
#pragma unroll
    for (int j = 0; j < 8; ++j) { int i = base + j; if (i < N) rowptr[i] = run; run += v[j]; }
}

__global__ void scanB2(int* __restrict__ bsum, int nb, int* __restrict__ rowptrs, int N) {
    int* bs = bsum + blockIdx.x * 128;
    __shared__ int lds[128];
    int tid = threadIdx.x;
    int v = (tid < nb) ? bs[tid] : 0;
    lds[tid] = v; __syncthreads();
    for (int d = 1; d < 128; d <<= 1) {
        int t2 = (tid >= d) ? lds[tid - d] : 0;
        __syncthreads();
        lds[tid] += t2;
        __syncthreads();
    }
    if (tid < nb) bs[tid] = lds[tid] - v;
    if (tid == 127) rowptrs[(size_t)blockIdx.x * (N + 1) + N] = lds[127];
}

__global__ void scanC2(int* __restrict__ rowptrs, const int* __restrict__ bsum, int N) {
    int i = blockIdx.x * 256 + threadIdx.x;
    if (i < N) rowptrs[(size_t)blockIdx.y * (N + 1) + i] += bsum[blockIdx.y * 128 + (i >> 11)];
}

// ---------------------------------------------------------------- encoders (first linear+relu)
__global__ void enc(const float* __restrict__ ctrs, const float* __restrict__ feats,
                    const float* __restrict__ w_in1, const float* __restrict__ b_in1,
                    const float* __restrict__ w_seg1, const float* __restrict__ b_seg1,
                    unsigned short* __restrict__ h_in, unsigned short* __restrict__ h_seg, int N) {
    int idx = blockIdx.x * 256 + threadIdx.x;
    if (idx >= N * 128) return;
    int n = idx >> 7, c = idx & 127;
    float x0 = ctrs[2 * n], x1 = ctrs[2 * n + 1];
    float h = fmaxf(x0 * w_in1[c] + x1 * w_in1[128 + c] + b_in1[c], 0.f);
    h_in[idx] = f2bf(h);
    x0 = feats[2 * n]; x1 = feats[2 * n + 1];
    h = fmaxf(x0 * w_seg1[c] + x1 * w_seg1[128 + c] + b_seg1[c], 0.f);
    h_seg[idx] = f2bf(h);
}

// ---------------------------------------------------------------- encoder GEMM (single plane)
enum { MODE_GN = 1, MODE_GNADD = 2 };

template <int MODE>
__global__ __launch_bounds__(256, 2) void gemm128(
    const unsigned short* __restrict__ A,
    const unsigned short* __restrict__ Bt,
    int M,
    const unsigned short* __restrict__ resb,
    float* __restrict__ outf,
    unsigned short* __restrict__ outb,
    const float* __restrict__ gw, const float* __restrict__ gb) {
    __shared__ char Asm[32768];
    __shared__ char Bsm[32768];
    const int tid = threadIdx.x;
    const int wv = tid >> 6, ln = tid & 63;
    const int q = ln >> 4, r = ln & 15;
    const int m0 = blockIdx.x * 128;

#pragma unroll
    for (int s = 0; s < 8; ++s) {
        int f = s * 256 + tid;
        int row = f >> 4, ck = f & 15;
        int grow = m0 + row; if (grow >= M) grow = M - 1;
        int4 v = *(const int4*)(A + (size_t)grow * 128 + ck * 8);
        *(int4*)(Asm + row * 256 + ((ck * 16) ^ ((row & 7) << 4))) = v;
    }
#pragma unroll
    for (int s = 0; s < 8; ++s) {
        int f = s * 256 + tid;
        int c = f >> 4, ck = f & 15;
        int4 v = *(const int4*)(Bt + c * 128 + ck * 8);
        *(int4*)(Bsm + c * 256 + ((ck * 16) ^ ((c & 7) << 4))) = v;
    }
    __syncthreads();

    f32x4 acc[2][8];
#pragma unroll
    for (int fj = 0; fj < 2; ++fj)
#pragma unroll
        for (int ci = 0; ci < 8; ++ci) acc[fj][ci] = (f32x4)(0.f);

#pragma unroll
    for (int k0 = 0; k0 < 128; k0 += 32) {
        int kb = k0 * 2 + q * 16;
        bf16x8 wf[8], ff[2];
#pragma unroll
        for (int ci = 0; ci < 8; ++ci) {
            int c = ci * 16 + r;
            wf[ci] = *(const bf16x8*)(Bsm + c * 256 + (kb ^ ((c & 7) << 4)));
        }
#pragma unroll
        for (int fj = 0; fj < 2; ++fj) {
            int row = wv * 32 + fj * 16 + r;
            ff[fj] = *(const bf16x8*)(Asm + row * 256 + (kb ^ ((row & 7) << 4)));
        }
#pragma unroll
        for (int fj = 0; fj < 2; ++fj)
#pragma unroll
            for (int ci = 0; ci < 8; ++ci)
                acc[fj][ci] = __builtin_amdgcn_mfma_f32_16x16x32_bf16(wf[ci], ff[fj], acc[fj][ci], 0, 0, 0);
    }

#pragma unroll
    for (int fj = 0; fj < 2; ++fj) {
        float s = 0.f;
#pragma unroll
        for (int ci = 0; ci < 8; ++ci) {
            f32x4 a = acc[fj][ci];
            s += a[0] + a[1] + a[2] + a[3];
        }
        s += __shfl_xor(s, 16); s += __shfl_xor(s, 32);
        float mean = s * (1.f / 128.f);
        float vs = 0.f;
#pragma unroll
        for (int ci = 0; ci < 8; ++ci) {
            f32x4 a = acc[fj][ci];
#pragma unroll
            for (int j = 0; j < 4; ++j) { float d = a[j] - mean; vs += d * d; }
        }
        vs += __shfl_xor(vs, 16); vs += __shfl_xor(vs, 32);
        float inv = rsqrtf(vs * (1.f / 128.f) + 1e-5f);
        int row = m0 + wv * 32 + fj * 16 + r;
        if (row < M) {
#pragma unroll
            for (int ci = 0; ci < 8; ++ci) {
                int col = ci * 16 + q * 4;
                f32x4 a = acc[fj][ci];
                float4 gv = *(const float4*)(gw + col);
                float4 bv = *(const float4*)(gb + col);
                float y0 = (a[0] - mean) * inv * gv.x + bv.x;
                float y1 = (a[1] - mean) * inv * gv.y + bv.y;
                float y2 = (a[2] - mean) * inv * gv.z + bv.z;
                float y3 = (a[3] - mean) * inv * gv.w + bv.w;
                if (MODE == MODE_GNADD) {
                    int2 rv = *(const int2*)(resb + (size_t)row * 128 + col);
                    y0 = fmaxf(y0 + bfl((unsigned)rv.x), 0.f);
                    y1 = fmaxf(y1 + bfh((unsigned)rv.x), 0.f);
                    y2 = fmaxf(y2 + bfl((unsigned)rv.y), 0.f);
                    y3 = fmaxf(y3 + bfh((unsigned)rv.y), 0.f);
                    if (outf) {
                        float4 o; o.x = y0; o.y = y1; o.z = y2; o.w = y3;
                        *(float4*)(outf + (size_t)row * 128 + col) = o;
                    }
                }
                unsigned lo = (unsigned)f2bf(y0) | ((unsigned)f2bf(y1) << 16);
                unsigned hi = (unsigned)f2bf(y2) | ((unsigned)f2bf(y3) << 16);
                int2 pk; pk.x = (int)lo; pk.y = (int)hi;
                *(int2*)(outb + (size_t)row * 128 + col) = pk;
            }
        }
    }
}

// ---------------------------------------------------------------- fused iteration kernel
// bf16 agg tile [64 rows][256B], m97-style swizzle (byte ^= (row&7)<<4).
// Per type: wave's 16 consecutive nodes = one contiguous CSR span -> flattened
// segment-reduce: chunk-load edge words, readlane broadcast, 8 rows in flight,
// flush (packed bf16 ds_write_b32, conflict-free) on u-change. MFMA A-feed is a
// direct bf16x8 read. LDS 48KB -> 3 blocks/CU.
template <int LASTI>
__global__ __launch_bounds__(256, 3) void fuse_gemm(
    const unsigned* __restrict__ featA,       // [N][64] packed 2xbf16 words
    unsigned short* __restrict__ featB,       // [N][128] bf16 out
    float* __restrict__ featf,                // [N][128] f32 out (LASTI)
    const unsigned short* __restrict__ Bt15,  // 15 planes
    const unsigned short* __restrict__ Bc2,   // ctr2 plane
    const int* __restrict__ rowptrs,          // 14*(N+1)
    const int* __restrict__ edata,
    int N, int E, int E2,
    const float* __restrict__ gw1, const float* __restrict__ gb1,
    const float* __restrict__ gw2, const float* __restrict__ gb2) {
    __shared__ char aggC[16384];   // 64 x 256B bf16 tile (doubles as P)
    __shared__ char Bsm[32768];
    const int tid = threadIdx.x;
    const int wv = tid >> 6, ln = tid & 63;
    const int q = ln >> 4, r = ln & 15;
    const int m0 = blockIdx.x * 64;
    const int row = wv * 16 + r;
    const int swB = (row & 7) << 4;
    const int g0 = m0 + wv * 16;

    f32x4 acc[8];
#pragma unroll
    for (int ci = 0; ci < 8; ++ci) acc[ci] = (f32x4)(0.f);

#define FLUSH_RUN() { \
    unsigned pk = (unsigned)f2bf(a0) | ((unsigned)f2bf(a1) << 16); \
    *(unsigned*)(aggC + ucur * 256 + ((ln * 4) ^ ((ucur & 7) << 4))) = pk; }
#define MERGE(w, p) { \
    int uu = (w) >> 18; \
    if (uu != ucur) { if (ucur >= 0) FLUSH_RUN(); ucur = uu; a0 = 0.f; a1 = 0.f; } \
    a0 += bfl(p); a1 += bfh(p); }

    for (int t = 0; t < 15; ++t) {
        // per-type CSR span (issue early; hides under Bsm staging)
        int r0 = 0, nE = 0;
        if (t > 0) {
            int tt = t - 1;
            const int* rp = rowptrs + (size_t)tt * (N + 1);
            r0 = rp[g0];
            nE = rp[g0 + 16] - r0;
        }
        __syncthreads();  // previous MFMA done with Bsm
        // stage W_t
        {
            const unsigned short* Bp = Bt15 + (size_t)t * 16384;
#pragma unroll
            for (int s = 0; s < 8; ++s) {
                int f = s * 256 + tid;
                int c = f >> 4, ck = f & 15;
                int4 v = *(const int4*)(Bp + c * 128 + ck * 8);
                *(int4*)(Bsm + c * 256 + ((ck * 16) ^ ((c & 7) << 4))) = v;
            }
        }
        // init this wave's 16 aggC rows
        if (t == 0) {
#pragma unroll
            for (int k = 0; k < 4; ++k) {
                int lr = wv * 16 + k * 4 + (ln >> 4);
                uint4 v = *(const uint4*)(featA + (size_t)(m0 + lr) * 64 + (ln & 15) * 4);
                *(uint4*)(aggC + lr * 256 + (((ln & 15) * 16) ^ ((lr & 7) << 4))) = v;
            }
        } else {
            uint4 z; z.x = 0; z.y = 0; z.z = 0; z.w = 0;
#pragma unroll
            for (int k = 0; k < 4; ++k) {
                int lr = wv * 16 + k * 4 + (ln >> 4);
                *(uint4*)(aggC + lr * 256 + (((ln & 15) * 16) ^ ((lr & 7) << 4))) = z;
            }
            // flattened segment-reduce over this wave's contiguous edge span
            int tt = t - 1;
            size_t base = (tt <= 11) ? (size_t)tt * E : (size_t)12 * E + (size_t)(tt - 12) * E2;
            const int* ed = edata + base;
            int ucur = -1; float a0 = 0.f, a1 = 0.f;
            for (int cb = 0; cb < nE; cb += 64) {
                int cnt = nE - cb; if (cnt > 64) cnt = 64;
                int myw = (ln < cnt) ? ed[r0 + cb + ln] : 0;
                int j = 0;
                for (; j + 8 <= cnt; j += 8) {
                    int w0 = __builtin_amdgcn_readlane(myw, j);
                    int w1 = __builtin_amdgcn_readlane(myw, j + 1);
                    int w2 = __builtin_amdgcn_readlane(myw, j + 2);
                    int w3 = __builtin_amdgcn_readlane(myw, j + 3);
                    int w4 = __builtin_amdgcn_readlane(myw, j + 4);
                    int w5 = __builtin_amdgcn_readlane(myw, j + 5);
                    int w6 = __builtin_amdgcn_readlane(myw, j + 6);
                    int w7 = __builtin_amdgcn_readlane(myw, j + 7);
                    unsigned p0 = featA[(size_t)(w0 & 0x3FFFF) * 64 + ln];
                    unsigned p1 = featA[(size_t)(w1 & 0x3FFFF) * 64 + ln];
                    unsigned p2 = featA[(size_t)(w2 & 0x3FFFF) * 64 + ln];
                    unsigned p3 = featA[(size_t)(w3 & 0x3FFFF) * 64 + ln];
                    unsigned p4 = featA[(size_t)(w4 & 0x3FFFF) * 64 + ln];
                    unsigned p5 = featA[(size_t)(w5 & 0x3FFFF) * 64 + ln];
                    unsigned p6 = featA[(size_t)(w6 & 0x3FFFF) * 64 + ln];
                    unsigned p7 = featA[(size_t)(w7 & 0x3FFFF) * 64 + ln];
                    MERGE(w0, p0); MERGE(w1, p1); MERGE(w2, p2); MERGE(w3, p3);
                    MERGE(w4, p4); MERGE(w5, p5); MERGE(w6, p6); MERGE(w7, p7);
                }
                for (; j + 4 <= cnt; j += 4) {
                    int w0 = __builtin_amdgcn_readlane(myw, j);
                    int w1 = __builtin_amdgcn_readlane(myw, j + 1);
                    int w2 = __builtin_amdgcn_readlane(myw, j + 2);
                    int w3 = __builtin_amdgcn_readlane(myw, j + 3);
                    unsigned p0 = featA[(size_t)(w0 & 0x3FFFF) * 64 + ln];
                    unsigned p1 = featA[(size_t)(w1 & 0x3FFFF) * 64 + ln];
                    unsigned p2 = featA[(size_t)(w2 & 0x3FFFF) * 64 + ln];
                    unsigned p3 = featA[(size_t)(w3 & 0x3FFFF) * 64 + ln];
                    MERGE(w0, p0); MERGE(w1, p1); MERGE(w2, p2); MERGE(w3, p3);
                }
                for (; j < cnt; ++j) {
                    int w0 = __builtin_amdgcn_readlane(myw, j);
                    unsigned p0 = featA[(size_t)(w0 & 0x3FFFF) * 64 + ln];
                    MERGE(w0, p0);
                }
            }
            if (ucur >= 0) FLUSH_RUN();
        }
        __syncthreads();  // Bsm ready (aggC rows are wave-own)
        // MFMA accumulate: acc += agg @ W_t
#pragma unroll
        for (int k0 = 0; k0 < 128; k0 += 32) {
            int kb = k0 * 2 + q * 16;
            bf16x8 ff = *(const bf16x8*)(aggC + row * 256 + (kb ^ swB));
#pragma unroll
            for (int ci = 0; ci < 8; ++ci) {
                int c = ci * 16 + r;
                bf16x8 wf = *(const bf16x8*)(Bsm + c * 256 + (kb ^ ((c & 7) << 4)));
                acc[ci] = __builtin_amdgcn_mfma_f32_16x16x32_bf16(wf, ff, acc[ci], 0, 0, 0);
            }
        }
    }

    // ---- epilogue 1: GN(norm) + ReLU -> py (bf16 packed)
    int2 py[8];
    {
        float s = 0.f;
#pragma unroll
        for (int ci = 0; ci < 8; ++ci) {
            f32x4 a = acc[ci];
            s += a[0] + a[1] + a[2] + a[3];
        }
        s += __shfl_xor(s, 16); s += __shfl_xor(s, 32);
        float mean = s * (1.f / 128.f);
        float vs = 0.f;
#pragma unroll
        for (int ci = 0; ci < 8; ++ci) {
            f32x4 a = acc[ci];
#pragma unroll
            for (int j = 0; j < 4; ++j) { float d = a[j] - mean; vs += d * d; }
        }
        vs += __shfl_xor(vs, 16); vs += __shfl_xor(vs, 32);
        float inv = rsqrtf(vs * (1.f / 128.f) + 1e-5f);
#pragma unroll
        for (int ci = 0; ci < 8; ++ci) {
            int cl = ci * 16 + q * 4;
            f32x4 a = acc[ci];
            float4 gv = *(const float4*)(gw1 + cl);
            float4 bv = *(const float4*)(gb1 + cl);
            float y0 = fmaxf((a[0] - mean) * inv * gv.x + bv.x, 0.f);
            float y1 = fmaxf((a[1] - mean) * inv * gv.y + bv.y, 0.f);
            float y2 = fmaxf((a[2] - mean) * inv * gv.z + bv.z, 0.f);
            float y3 = fmaxf((a[3] - mean) * inv * gv.w + bv.w, 0.f);
            py[ci].x = (int)((unsigned)f2bf(y0) | ((unsigned)f2bf(y1) << 16));
            py[ci].y = (int)((unsigned)f2bf(y2) | ((unsigned)f2bf(y3) << 16));
        }
    }
    __syncthreads();  // all waves done reading aggC/Bsm
    // store P (bf16 tile in aggC) + stage ctr2 weights
#pragma unroll
    for (int ci = 0; ci < 8; ++ci)
        *(int2*)(aggC + row * 256 + ((ci * 32 + q * 8) ^ swB)) = py[ci];
#pragma unroll
    for (int s = 0; s < 8; ++s) {
        int f = s * 256 + tid;
        int c = f >> 4, ck = f & 15;
        int4 v = *(const int4*)(Bc2 + c * 128 + ck * 8);
        *(int4*)(Bsm + c * 256 + ((ck * 16) ^ ((c & 7) << 4))) = v;
    }
    __syncthreads();

    // ---- second GEMM: acc2 = P @ ctr2
    f32x4 acc2[8];
#pragma unroll
    for (int ci = 0; ci < 8; ++ci) acc2[ci] = (f32x4)(0.f);
#pragma unroll
    for (int k0 = 0; k0 < 128; k0 += 32) {
        int kb = k0 * 2 + q * 16;
        bf16x8 ff = *(const bf16x8*)(aggC + row * 256 + (kb ^ swB));
#pragma unroll
        for (int ci = 0; ci < 8; ++ci) {
            int c = ci * 16 + r;
            bf16x8 wf = *(const bf16x8*)(Bsm + c * 256 + (kb ^ ((c & 7) << 4)));
            acc2[ci] = __builtin_amdgcn_mfma_f32_16x16x32_bf16(wf, ff, acc2[ci], 0, 0, 0);
        }
    }

    // ---- epilogue 2: GN(ctr2) + residual + ReLU -> featB (+featf)
    {
        float s = 0.f;
#pragma unroll
        for (int ci = 0; ci < 8; ++ci) {
            f32x4 a = acc2[ci];
            s += a[0] + a[1] + a[2] + a[3];
        }
        s += __shfl_xor(s, 16); s += __shfl_xor(s, 32);
        float mean = s * (1.f / 128.f);
        float vs = 0.f;
#pragma unroll
        for (int ci = 0; ci < 8; ++ci) {
            f32x4 a = acc2[ci];
#pragma unroll
            for (int j = 0; j < 4; ++j) { float d = a[j] - mean; vs += d * d; }
        }
        vs += __shfl_xor(vs, 16); vs += __shfl_xor(vs, 32);
        float inv = rsqrtf(vs * (1.f / 128.f) + 1e-5f);
        int grow = m0 + row;
        const unsigned short* fA16 = (const unsigned short*)featA;
#pragma unroll
        for (int ci = 0; ci < 8; ++ci) {
            int cl = ci * 16 + q * 4;
            f32x4 a = acc2[ci];
            float4 gv = *(const float4*)(gw2 + cl);
            float4 bv = *(const float4*)(gb2 + cl);
            int2 rv = *(const int2*)(fA16 + (size_t)grow * 128 + cl);
            float y0 = fmaxf((a[0] - mean) * inv * gv.x + bv.x + bfl((unsigned)rv.x), 0.f);
            float y1 = fmaxf((a[1] - mean) * inv * gv.y + bv.y + bfh((unsigned)rv.x), 0.f);
            float y2 = fmaxf((a[2] - mean) * inv * gv.z + bv.z + bfl((unsigned)rv.y), 0.f);
            float y3 = fmaxf((a[3] - mean) * inv * gv.w + bv.w + bfh((unsigned)rv.y), 0.f);
            unsigned lo = (unsigned)f2bf(y0) | ((unsigned)f2bf(y1) << 16);
            unsigned hi = (unsigned)f2bf(y2) | ((unsigned)f2bf(y3) << 16);
            int2 pk; pk.x = (int)lo; pk.y = (int)hi;
            *(int2*)(featB + (size_t)grow * 128 + cl) = pk;
            if (LASTI) {
                float4 o; o.x = y0; o.y = y1; o.z = y2; o.w = y3;
                *(float4*)(featf + (size_t)grow * 128 + cl) = o;
            }
        }
    }
#undef MERGE
#undef FLUSH_RUN
}

// ---------------------------------------------------------------- launch
extern "C" void kernel_launch(void* const* d_in, const int* in_sizes, int n_in,
                              void* d_out, int out_size, void* d_ws, size_t ws_size,
                              hipStream_t stream) {
    const float* ctrs = (const float*)d_in[0];
    const float* feats = (const float*)d_in[1];
    const float* w_in1 = (const float*)d_in[2];
    const float* b_in1 = (const float*)d_in[3];
    const float* w_in2 = (const float*)d_in[4];
    const float* g_in = (const float*)d_in[5];
    const float* be_in = (const float*)d_in[6];
    const float* w_seg1 = (const float*)d_in[7];
    const float* b_seg1 = (const float*)d_in[8];
    const float* w_seg2 = (const float*)d_in[9];
    const float* g_seg = (const float*)d_in[10];
    const float* be_seg = (const float*)d_in[11];
    const float* ctr_w = (const float*)d_in[12];
    const float* pre_w = (const float*)d_in[13];
    const float* suc_w = (const float*)d_in[14];
    const float* left_w = (const float*)d_in[15];
    const float* right_w = (const float*)d_in[16];
    const float* norm_g = (const float*)d_in[17];
    const float* norm_b = (const float*)d_in[18];
    const float* ctr2_w = (const float*)d_in[19];
    const float* ctr2_g = (const float*)d_in[20];
    const float* ctr2_b = (const float*)d_in[21];
    const int* pre_u = (const int*)d_in[22];
    const int* pre_v = (const int*)d_in[23];
    const int* suc_u = (const int*)d_in[24];
    const int* suc_v = (const int*)d_in[25];
    const int* left_u = (const int*)d_in[26];
    const int* left_v = (const int*)d_in[27];
    const int* right_u = (const int*)d_in[28];
    const int* right_v = (const int*)d_in[29];

    const int N = in_sizes[0] / 2;
    const int E = in_sizes[22] / 6;
    const int E2 = in_sizes[26];
    const int Mtot = 12 * E + 2 * E2;

    char* ws = (char*)d_ws;
    size_t off = 0;
    auto alloc = [&](size_t b) { void* p = ws + off; off += (b + 255) & ~(size_t)255; return p; };

    unsigned short* Btw = (unsigned short*)alloc((size_t)66 * 16384 * 2);
    unsigned short* featb = (unsigned short*)alloc((size_t)N * 128 * 2);
    unsigned short* feat1b = (unsigned short*)alloc((size_t)N * 128 * 2);
    int* rowptrs = (int*)alloc((size_t)14 * (N + 1) * 4);
    int* cnt14 = (int*)alloc((size_t)14 * N * 4);
    int* bsum = (int*)alloc((size_t)14 * 128 * 4);
    int* edata = (int*)alloc((size_t)Mtot * 4);

    float* featf = (float*)d_out;

    wprep<<<dim3((66 * 16384 + 255) / 256), dim3(256), 0, stream>>>(
        w_in2, w_seg2, ctr_w, pre_w, suc_w, left_w, right_w, ctr2_w, Btw);

    // per-type CSR build
    hipMemsetAsync(cnt14, 0, (size_t)14 * N * 4, stream);
    dim3 eg((Mtot + 255) / 256);
    edge_count14<<<eg, dim3(256), 0, stream>>>(
        pre_u, pre_v, suc_u, suc_v, left_u, left_v, right_u, right_v,
        E, E2, Mtot, N, cnt14);
    int nb = (N + 2047) / 2048;
    scanA2<<<dim3(nb, 14), dim3(256), 0, stream>>>(cnt14, N, rowptrs, bsum);
    scanB2<<<dim3(14), dim3(128), 0, stream>>>(bsum, nb, rowptrs, N);
    scanC2<<<dim3((N + 255) / 256, 14), dim3(256), 0, stream>>>(rowptrs, bsum, N);
    hipMemsetAsync(cnt14, 0, (size_t)14 * N * 4, stream);
    edge_fill14<<<eg, dim3(256), 0, stream>>>(
        pre_u, pre_v, suc_u, suc_v, left_u, left_v, right_u, right_v,
        E, E2, Mtot, N, rowptrs, cnt14, edata);

    // encoders -> featb (= feat^0)
    enc<<<dim3((N * 128 + 255) / 256), dim3(256), 0, stream>>>(
        ctrs, feats, w_in1, b_in1, w_seg1, b_seg1, feat1b, featb, N);
    const int gblk = (N + 127) / 128;
    gemm128<MODE_GN><<<dim3(gblk), dim3(256), 0, stream>>>(
        feat1b, Btw, N, nullptr, nullptr, feat1b, g_in, be_in);
    gemm128<MODE_GNADD><<<dim3(gblk), dim3(256), 0, stream>>>(
        featb, Btw + 16384, N, feat1b, nullptr, featb, g_seg, be_seg);

    // fused iterations (ping-pong featb <-> feat1b)
    const int fblk = (N + 63) / 64;
    for (int i = 0; i < 4; ++i) {
        const unsigned* fA = (const unsigned*)((i & 1) ? feat1b : featb);
        unsigned short* fB = (i & 1) ? featb : feat1b;
        const unsigned short* Bt15 = Btw + (size_t)(2 + i * 15) * 16384;
        const unsigned short* Bc2 = Btw + (size_t)(62 + i) * 16384;
        if (i == 3)
            fuse_gemm<1><<<dim3(fblk), dim3(256), 0, stream>>>(
                fA, fB, featf, Bt15, Bc2, rowptrs, edata, N, E, E2,
                norm_g + i * 128, norm_b + i * 128, ctr2_g + i * 128, ctr2_b + i * 128);
        else
            fuse_gemm<0><<<dim3(fblk), dim3(256), 0, stream>>>(
                fA, fB, featf, Bt15, Bc2, rowptrs, edata, N, E, E2,
                norm_g + i * 128, norm_b + i * 128, ctr2_g + i * 128, ctr2_b + i * 128);
    }
}